// Round 3
// baseline (121.644 us; speedup 1.0000x reference)
//
#include <hip/hip_runtime.h>
#include <hip/hip_bf16.h>

#define N_NODES 100000
#define N_EDGES 1600000
#define K_DIM 128
#define N_DIM 128
#define BM_WORDS 3125        // ceil(100000/32)
#define PART_STRIDE 3136     // per-block partial-mask stride, 64B-multiple
#define FLAG_BLOCKS 256
#define PART_OFF 4096        // word offset of partials in d_ws
#define BROWS 64             // rows per gemm block (48 KB LDS -> 3 blocks/CU)

typedef __attribute__((ext_vector_type(8))) short bf16x8;   // 8 bf16 = 4 VGPRs
typedef __attribute__((ext_vector_type(4))) float f32x4;    // MFMA accumulator

__device__ inline unsigned short f2bf(float f) {
    __hip_bfloat16 b = __float2bfloat16(f);
    return __builtin_bit_cast(unsigned short, b);
}

// Phase A: per-block private bitmask in LDS (LDS atomics only), written to a
// DISJOINT partial-mask region with plain coalesced stores. Zero global
// atomics -> no hot-line serialization at the LLC.
__global__ __launch_bounds__(256)
void flag_partial(const int* __restrict__ ei, unsigned int* __restrict__ parts) {
    __shared__ unsigned int lbm[BM_WORDS];
    for (int i = threadIdx.x; i < BM_WORDS; i += 256) lbm[i] = 0;
    __syncthreads();

    // int64-as-int32-pairs vs int32 sniff (high words of non-neg int64 are 0)
    bool is64 = ((ei[1] | ei[3] | ei[5] | ei[7]) == 0);
    const int base = blockIdx.x * (N_EDGES / FLAG_BLOCKS);   // 6250 edges/block
    if (is64) {
        // col array at words [2E, 4E), stride-2; uint4 = 2 edges. Alignment:
        // 4*(2E + 2*base) % 16 == 0 since base % 2 == 0.
        const uint4* p = (const uint4*)(ei + 2 * N_EDGES + 2 * base);
        for (int t = threadIdx.x; t < 3125; t += 256) {
            uint4 v = p[t];
            atomicOr(&lbm[v.x >> 5], 1u << (v.x & 31));
            atomicOr(&lbm[v.z >> 5], 1u << (v.z & 31));
        }
    } else {
        const uint2* p = (const uint2*)(ei + N_EDGES + base);  // base even -> 8B-aligned
        for (int t = threadIdx.x; t < 3125; t += 256) {
            uint2 v = p[t];
            atomicOr(&lbm[v.x >> 5], 1u << (v.x & 31));
            atomicOr(&lbm[v.y >> 5], 1u << (v.y & 31));
        }
    }
    __syncthreads();

    unsigned int* dst = parts + (size_t)blockIdx.x * PART_STRIDE;
    for (int i = threadIdx.x; i < BM_WORDS; i += 256) dst[i] = lbm[i];
}

// out[n,:] = hasedge[n] ? (x @ W)[n,:] : 0.  fp32 in, bf16 MFMA, fp32 store.
// 64 rows/block, 48 KB LDS -> 3 blocks/CU (12 waves/CU, was 8). Unpadded
// XOR-swizzled LDS (byte ^= (row&7)<<4): every ds_read_b128/ds_write_b128 in
// the kernel lands at the uniform 8 lanes per 4-bank group minimum
// (hand-verified per access pattern), replacing the +8-short padding that
// cost 2x LDS footprint.
// Inline flag-reduce: each block ORs the 256 partial masks for its 2 words.
__global__ __launch_bounds__(256, 3)
void gemm_fused(const float* __restrict__ xf,
                const float* __restrict__ wf,
                const unsigned int* __restrict__ parts,
                float* __restrict__ out) {
    __shared__ __attribute__((aligned(16))) unsigned short ldsW[N_DIM * 128];  // 32 KB
    __shared__ __attribute__((aligned(16))) unsigned short ldsA[BROWS * 128];  // 16 KB
    __shared__ unsigned int lmask[4][2];     // [contrib wave][mask word]

    const int tid  = threadIdx.x;
    const int lane = tid & 63;
    const int wave = tid >> 6;
    const int rb0  = blockIdx.x * BROWS;

    // ---- inline flag-reduce: thread p ORs partial p's 2 words for this block
    {
        const unsigned int* p =
            parts + (size_t)tid * PART_STRIDE + blockIdx.x * 2;
        uint2 pv = *(const uint2*)p;   // 8B-aligned: stride & offset both even
#pragma unroll
        for (int off = 32; off; off >>= 1) {
            pv.x |= __shfl_xor(pv.x, off);
            pv.y |= __shfl_xor(pv.y, off);
        }
        if (lane == 0) { lmask[wave][0] = pv.x; lmask[wave][1] = pv.y; }
    }

    // ---- stage W (transpose-read: coalesced 256B global segments along n;
    // swizzled ds_write_b128, uniform bank spread)
#pragma unroll
    for (int i = 0; i < 8; ++i) {
        int c  = i * 256 + tid;           // 0..2047
        int n  = c & 127;
        int k0 = (c >> 7) << 3;           // 0,8,...,120
        unsigned short tmp[8];
#pragma unroll
        for (int j = 0; j < 8; ++j) tmp[j] = f2bf(wf[(k0 + j) * N_DIM + n]);
        int byte = n * 256 + k0 * 2;
        byte ^= (n & 7) << 4;
        *(uint4*)((char*)ldsW + byte) = *(const uint4*)tmp;
    }

    // ---- stage A: 64 rows x 128 k. Two float4 per thread-chunk (32B of one
    // row, 4x256B contiguous segments per load instr), one ds_write_b128.
#pragma unroll
    for (int i = 0; i < 4; ++i) {
        int c  = i * 256 + tid;           // chunk 0..1023 (16 chunks/row)
        int rl = c >> 4;                  // local row 0..63
        int k8 = c & 15;                  // 8-elem k-chunk
        int rg = rb0 + rl;
        if (rg >= N_NODES) rg = N_NODES - 1;          // clamp: loads stay safe
        f32x4 v0 = *(const f32x4*)(xf + (size_t)rg * K_DIM + k8 * 8);
        f32x4 v1 = *(const f32x4*)(xf + (size_t)rg * K_DIM + k8 * 8 + 4);
        unsigned short t8[8];
#pragma unroll
        for (int j = 0; j < 4; ++j) {
            t8[j]     = f2bf(v0[j]);
            t8[4 + j] = f2bf(v1[j]);
        }
        int byte = rl * 256 + k8 * 16;
        byte ^= (rl & 7) << 4;
        *(uint4*)((char*)ldsA + byte) = *(const uint4*)t8;
    }
    __syncthreads();

    const int m    = lane & 15;   // A row / B col / C col
    const int quad = lane >> 4;   // 0..3
    const int arow = wave * 16 + m;       // wave owns 16 rows

    f32x4 acc[8];
#pragma unroll
    for (int t = 0; t < 8; ++t) acc[t] = (f32x4){0.f, 0.f, 0.f, 0.f};

#pragma unroll
    for (int kk = 0; kk < 4; ++kk) {
        const int kbase = kk * 32 + quad * 8;
        int abyte = (arow * 128 + kbase) * 2;
        abyte ^= (arow & 7) << 4;
        bf16x8 af = *(const bf16x8*)((const char*)ldsA + abyte);
#pragma unroll
        for (int t = 0; t < 8; ++t) {
            int bn = t * 16 + m;
            int bbyte = (bn * 128 + kbase) * 2;
            bbyte ^= (bn & 7) << 4;      // bn&7 == m&7
            bf16x8 bfrag = *(const bf16x8*)((const char*)ldsW + bbyte);
            acc[t] = __builtin_amdgcn_mfma_f32_16x16x32_bf16(af, bfrag, acc[t], 0, 0, 0);
        }
    }

    // combine the 4 waves' partial ORs -> this block's 2 mask words
    const unsigned int fm0 = lmask[0][0] | lmask[1][0] | lmask[2][0] | lmask[3][0];
    const unsigned int fm1 = lmask[0][1] | lmask[1][1] | lmask[2][1] | lmask[3][1];

    // C/D layout: col = lane&15, row = quad*4 + reg
#pragma unroll
    for (int r = 0; r < 4; ++r) {
        int lrow = wave * 16 + quad * 4 + r;   // 0..63
        int orow = rb0 + lrow;
        if (orow < N_NODES) {
            unsigned int w = (lrow & 32) ? fm1 : fm0;
            float fmul = ((w >> (lrow & 31)) & 1) ? 1.0f : 0.0f;
#pragma unroll
            for (int t = 0; t < 8; ++t)
                out[(size_t)orow * N_DIM + t * 16 + m] = acc[t][r] * fmul;
        }
    }
}

extern "C" void kernel_launch(void* const* d_in, const int* in_sizes, int n_in,
                              void* d_out, int out_size, void* d_ws, size_t ws_size,
                              hipStream_t stream) {
    const float* x = (const float*)d_in[0];
    const float* w = (const float*)d_in[1];
    // d_in[2] (att) is mathematically irrelevant: normalized attention weights
    // sum to s/(s+1e-16) == 1 per segment in fp32, and the reference
    // aggregates h[col]*alpha into col, so out[n] = h[n] (or 0 if no in-edge).
    const int* ei = (const int*)d_in[3];
    float* out = (float*)d_out;

    unsigned int* parts = (unsigned int*)d_ws + PART_OFF; // 256 partial masks

    flag_partial<<<FLAG_BLOCKS, 256, 0, stream>>>(ei, parts);
    gemm_fused<<<(N_NODES + BROWS - 1) / BROWS, 256, 0, stream>>>(x, w, parts, out);
}

// Round 4
// 120.129 us; speedup vs baseline: 1.0126x; 1.0126x over previous
//
#include <hip/hip_runtime.h>
#include <hip/hip_bf16.h>

#define N_NODES 100000
#define N_EDGES 1600000
#define K_DIM 128
#define N_DIM 128
#define BM_WORDS 3125        // ceil(100000/32)
#define PART_STRIDE 3136     // per-block partial-mask stride, 64B-multiple
#define FLAG_BLOCKS 256
#define WIMG_WORDS 8192      // 32 KB bf16 W LDS-image at d_ws words [0, 8192)
#define PART_OFF 8192        // word offset of partials in d_ws (moved past wimg)
#define BROWS 64             // rows per gemm block (48 KB LDS -> 3 blocks/CU)

typedef __attribute__((ext_vector_type(8))) short bf16x8;   // 8 bf16 = 4 VGPRs
typedef __attribute__((ext_vector_type(4))) float f32x4;    // MFMA accumulator

__device__ inline unsigned short f2bf(float f) {
    __hip_bfloat16 b = __float2bfloat16(f);
    return __builtin_bit_cast(unsigned short, b);
}

// Phase A: per-block private bitmask in LDS (LDS atomics only), written to a
// DISJOINT partial-mask region with plain coalesced stores. Zero global
// atomics -> no hot-line serialization at the LLC.
// Blocks 0..15 additionally build the 32 KB bf16 "LDS image" of W (column-
// major k-contiguous, XOR-swizzled) so the gemm can stage W with direct
// global_load_lds instead of 64 scalar loads + 64 cvts per thread.
// Rebuilt every launch -> workspace re-poisoning is harmless.
__global__ __launch_bounds__(256)
void flag_partial(const int* __restrict__ ei, const float* __restrict__ wf,
                  unsigned int* __restrict__ wimg,
                  unsigned int* __restrict__ parts) {
    __shared__ unsigned int lbm[BM_WORDS];

    // ---- W image (16 blocks x 128 threads x one 16B granule) — issued first
    // so its strided loads overlap the LDS zeroing + edge streaming below.
    if (blockIdx.x < 16 && threadIdx.x < 128) {
        int g  = blockIdx.x * 128 + threadIdx.x;   // granule 0..2047
        int n  = g >> 4;                           // W column (output ch)
        int k0 = (g & 15) << 3;                    // k-chunk base
        unsigned short tmp[8];
#pragma unroll
        for (int j = 0; j < 8; ++j) tmp[j] = f2bf(wf[(k0 + j) * N_DIM + n]);
        int byte = (n * 256 + k0 * 2) ^ ((n & 7) << 4);   // swizzled LDS image
        *(uint4*)((char*)wimg + byte) = *(const uint4*)tmp;
    }

    for (int i = threadIdx.x; i < BM_WORDS; i += 256) lbm[i] = 0;
    __syncthreads();

    // int64-as-int32-pairs vs int32 sniff (high words of non-neg int64 are 0)
    bool is64 = ((ei[1] | ei[3] | ei[5] | ei[7]) == 0);
    const int base = blockIdx.x * (N_EDGES / FLAG_BLOCKS);   // 6250 edges/block
    if (is64) {
        // col array at words [2E, 4E), stride-2; uint4 = 2 edges. Alignment:
        // 4*(2E + 2*base) % 16 == 0 since base % 2 == 0.
        const uint4* p = (const uint4*)(ei + 2 * N_EDGES + 2 * base);
        for (int t = threadIdx.x; t < 3125; t += 256) {
            uint4 v = p[t];
            atomicOr(&lbm[v.x >> 5], 1u << (v.x & 31));
            atomicOr(&lbm[v.z >> 5], 1u << (v.z & 31));
        }
    } else {
        const uint2* p = (const uint2*)(ei + N_EDGES + base);  // base even -> 8B-aligned
        for (int t = threadIdx.x; t < 3125; t += 256) {
            uint2 v = p[t];
            atomicOr(&lbm[v.x >> 5], 1u << (v.x & 31));
            atomicOr(&lbm[v.y >> 5], 1u << (v.y & 31));
        }
    }
    __syncthreads();

    unsigned int* dst = parts + (size_t)blockIdx.x * PART_STRIDE;
    for (int i = threadIdx.x; i < BM_WORDS; i += 256) dst[i] = lbm[i];
}

// out[n,:] = hasedge[n] ? (x @ W)[n,:] : 0.  fp32 in, bf16 MFMA, fp32 store.
// 64 rows/block, 48 KB LDS, 3 blocks/CU. Staging:
//   - A: 8 dwordx4 issued FIRST (oldest in VMEM queue), cvt+swizzled ds_write
//     while W streams in.
//   - W: 8 global_load_lds dwordx4 per wave-segment from the precomputed
//     32 KB LDS-image (identity mapping: source layout == LDS layout, so the
//     wave-uniform-dest constraint is satisfied; swizzle already applied).
// __syncthreads() drains vmcnt -> both LDS tiles complete before compute.
// Inline flag-reduce: each block ORs the 256 partial masks for its 2 words.
__global__ __launch_bounds__(256, 3)
void gemm_fused(const float* __restrict__ xf,
                const unsigned int* __restrict__ wimg,
                const unsigned int* __restrict__ parts,
                float* __restrict__ out) {
    __shared__ __attribute__((aligned(16))) unsigned short ldsW[N_DIM * 128];  // 32 KB
    __shared__ __attribute__((aligned(16))) unsigned short ldsA[BROWS * 128];  // 16 KB
    __shared__ unsigned int lmask[4][2];     // [contrib wave][mask word]

    const int tid  = threadIdx.x;
    const int lane = tid & 63;
    const int wave = tid >> 6;
    const int rb0  = blockIdx.x * BROWS;

    // ---- A global loads issued first: 64 rows x 128 k, coalesced dwordx4.
    f32x4 av[4][2];
#pragma unroll
    for (int i = 0; i < 4; ++i) {
        int c  = i * 256 + tid;           // chunk 0..1023 (16 chunks/row)
        int rl = c >> 4;                  // local row 0..63
        int k8 = c & 15;                  // 8-elem k-chunk
        int rg = rb0 + rl;
        if (rg >= N_NODES) rg = N_NODES - 1;          // clamp: loads stay safe
        av[i][0] = *(const f32x4*)(xf + (size_t)rg * K_DIM + k8 * 8);
        av[i][1] = *(const f32x4*)(xf + (size_t)rg * K_DIM + k8 * 8 + 4);
    }

    // ---- W: direct global->LDS (no VGPR round trip, no cvt). Each wave
    // copies 8 x 1KB; segments {i*4096 + wave*1024} tile [0, 32KB) uniquely.
#pragma unroll
    for (int i = 0; i < 8; ++i) {
        int off = i * 4096 + wave * 1024;            // bytes, wave-uniform
        __builtin_amdgcn_global_load_lds(
            (const __attribute__((address_space(1))) unsigned int*)
                ((const char*)wimg + off + lane * 16),
            (__attribute__((address_space(3))) unsigned int*)
                ((char*)ldsW + off),
            16, 0, 0);
    }

    // ---- inline flag-reduce: thread p ORs partial p's 2 words for this block
    {
        const unsigned int* p =
            parts + (size_t)tid * PART_STRIDE + blockIdx.x * 2;
        uint2 pv = *(const uint2*)p;   // 8B-aligned: stride & offset both even
#pragma unroll
        for (int off = 32; off; off >>= 1) {
            pv.x |= __shfl_xor(pv.x, off);
            pv.y |= __shfl_xor(pv.y, off);
        }
        if (lane == 0) { lmask[wave][0] = pv.x; lmask[wave][1] = pv.y; }
    }

    // ---- A: cvt to bf16, swizzled ds_write_b128
#pragma unroll
    for (int i = 0; i < 4; ++i) {
        int c  = i * 256 + tid;
        int rl = c >> 4;
        int k8 = c & 15;
        unsigned short t8[8];
#pragma unroll
        for (int j = 0; j < 4; ++j) {
            t8[j]     = f2bf(av[i][0][j]);
            t8[4 + j] = f2bf(av[i][1][j]);
        }
        int byte = (rl * 256 + k8 * 16) ^ ((rl & 7) << 4);
        *(uint4*)((char*)ldsA + byte) = *(const uint4*)t8;
    }
    __syncthreads();   // drains vmcnt(0) + lgkmcnt(0): W and A tiles complete

    const int m    = lane & 15;   // A row / B col / C col
    const int quad = lane >> 4;   // 0..3
    const int arow = wave * 16 + m;       // wave owns 16 rows

    f32x4 acc[8];
#pragma unroll
    for (int t = 0; t < 8; ++t) acc[t] = (f32x4){0.f, 0.f, 0.f, 0.f};

#pragma unroll
    for (int kk = 0; kk < 4; ++kk) {
        const int kbase = kk * 32 + quad * 8;
        int abyte = (arow * 256 + kbase * 2) ^ ((arow & 7) << 4);
        bf16x8 af = *(const bf16x8*)((const char*)ldsA + abyte);
#pragma unroll
        for (int t = 0; t < 8; ++t) {
            int bn = t * 16 + m;
            int bbyte = (bn * 256 + kbase * 2) ^ ((bn & 7) << 4);
            bf16x8 bfrag = *(const bf16x8*)((const char*)ldsW + bbyte);
            acc[t] = __builtin_amdgcn_mfma_f32_16x16x32_bf16(af, bfrag, acc[t], 0, 0, 0);
        }
    }

    // combine the 4 waves' partial ORs -> this block's 2 mask words
    const unsigned int fm0 = lmask[0][0] | lmask[1][0] | lmask[2][0] | lmask[3][0];
    const unsigned int fm1 = lmask[0][1] | lmask[1][1] | lmask[2][1] | lmask[3][1];

    // C/D layout: col = lane&15, row = quad*4 + reg
#pragma unroll
    for (int r = 0; r < 4; ++r) {
        int lrow = wave * 16 + quad * 4 + r;   // 0..63
        int orow = rb0 + lrow;
        if (orow < N_NODES) {
            unsigned int w = (lrow & 32) ? fm1 : fm0;
            float fmul = ((w >> (lrow & 31)) & 1) ? 1.0f : 0.0f;
#pragma unroll
            for (int t = 0; t < 8; ++t)
                out[(size_t)orow * N_DIM + t * 16 + m] = acc[t][r] * fmul;
        }
    }
}

extern "C" void kernel_launch(void* const* d_in, const int* in_sizes, int n_in,
                              void* d_out, int out_size, void* d_ws, size_t ws_size,
                              hipStream_t stream) {
    const float* x = (const float*)d_in[0];
    const float* w = (const float*)d_in[1];
    // d_in[2] (att) is mathematically irrelevant: normalized attention weights
    // sum to s/(s+1e-16) == 1 per segment in fp32, and the reference
    // aggregates h[col]*alpha into col, so out[n] = h[n] (or 0 if no in-edge).
    const int* ei = (const int*)d_in[3];
    float* out = (float*)d_out;

    unsigned int* wimg  = (unsigned int*)d_ws;            // 32 KB W LDS-image
    unsigned int* parts = (unsigned int*)d_ws + PART_OFF; // 256 partial masks

    flag_partial<<<FLAG_BLOCKS, 256, 0, stream>>>(ei, w, wimg, parts);
    gemm_fused<<<(N_NODES + BROWS - 1) / BROWS, 256, 0, stream>>>(x, wimg, parts, out);
}